// Round 12
// baseline (431.693 us; speedup 1.0000x reference)
//
#include <hip/hip_runtime.h>

typedef __attribute__((ext_vector_type(8))) short short8;
typedef __attribute__((ext_vector_type(4))) float floatx4;

constexpr int Bb = 2, Ss = 2048, Dd = 1024, Hh = 16, Pp = 128, DHh = 64;
constexpr int NS = Ss + Pp; // 2176

#define DEVI __device__ __forceinline__

#define SYNC_LDS()                                          \
  do {                                                      \
    asm volatile("s_waitcnt lgkmcnt(0)" ::: "memory");      \
    __builtin_amdgcn_s_barrier();                           \
  } while (0)
#define SYNC_VM()                                           \
  do {                                                      \
    asm volatile("s_waitcnt vmcnt(0)" ::: "memory");        \
    __builtin_amdgcn_s_barrier();                           \
  } while (0)

DEVI unsigned short f2bf(float f) {
  unsigned u = __float_as_uint(f);
  u += 0x7fffu + ((u >> 16) & 1u);
  return (unsigned short)(u >> 16);
}
DEVI float bf2f(unsigned short h) { return __uint_as_float(((unsigned)h) << 16); }

DEVI void gl_lds16(const unsigned short* g, unsigned short* l) {
  __builtin_amdgcn_global_load_lds((const __attribute__((address_space(1))) unsigned int*)g,
                                   (__attribute__((address_space(3))) unsigned int*)l, 16, 0, 0);
}

// ------- fused weight transpose + f32->bf16 for all 4 weights, one launch -------
__global__ __launch_bounds__(256) void wt_cvt_all_kernel(const float* __restrict__ qkv_w,
                                                         const float* __restrict__ merge_w,
                                                         const float* __restrict__ ln1_w,
                                                         const float* __restrict__ ln2_w,
                                                         unsigned short* __restrict__ qkv_wT,
                                                         unsigned short* __restrict__ merge_wT,
                                                         unsigned short* __restrict__ ln1_wT,
                                                         unsigned short* __restrict__ ln2_wT) {
  __shared__ float tl[32][33];
  int bid = blockIdx.x;
  const float* W;
  unsigned short* Wt;
  int K, N, bx, by;
  if (bid < 3072) {
    W = qkv_w; Wt = qkv_wT; K = 1024; N = 3072; bx = bid % 96; by = bid / 96;
  } else if (bid < 4096) {
    int b2 = bid - 3072; W = merge_w; Wt = merge_wT; K = 1024; N = 1024; bx = b2 % 32; by = b2 / 32;
  } else if (bid < 8192) {
    int b3 = bid - 4096; W = ln1_w; Wt = ln1_wT; K = 1024; N = 4096; bx = b3 % 128; by = b3 / 128;
  } else {
    int b4 = bid - 8192; W = ln2_w; Wt = ln2_wT; K = 4096; N = 1024; bx = b4 % 32; by = b4 / 32;
  }
  int n0 = bx * 32, k0 = by * 32;
  int tx = threadIdx.x & 31, ty = threadIdx.x >> 5;
#pragma unroll
  for (int j = 0; j < 4; j++)
    tl[ty + 8 * j][tx] = W[(long)(k0 + ty + 8 * j) * N + n0 + tx];
  __syncthreads();
#pragma unroll
  for (int j = 0; j < 4; j++)
    Wt[(long)(n0 + ty + 8 * j) * K + k0 + tx] = f2bf(tl[tx][ty + 8 * j]);
}

// ---------------- layernorm ----------------
__global__ __launch_bounds__(256) void ln_kernel(const float* __restrict__ x,
                                                 const float* __restrict__ g,
                                                 const float* __restrict__ bia,
                                                 unsigned short* __restrict__ out) {
  int row = blockIdx.x;
  int t = threadIdx.x;
  const float4* xr = (const float4*)(x + (long)row * Dd);
  float4 v = xr[t];
  float s1 = v.x + v.y + v.z + v.w;
  float s2 = v.x * v.x + v.y * v.y + v.z * v.z + v.w * v.w;
#pragma unroll
  for (int o = 1; o < 64; o <<= 1) {
    s1 += __shfl_xor(s1, o);
    s2 += __shfl_xor(s2, o);
  }
  __shared__ float r1[4], r2[4];
  int wid = t >> 6;
  if ((t & 63) == 0) { r1[wid] = s1; r2[wid] = s2; }
  __syncthreads();
  s1 = r1[0] + r1[1] + r1[2] + r1[3];
  s2 = r2[0] + r2[1] + r2[2] + r2[3];
  float mean = s1 * (1.0f / Dd);
  float var = s2 * (1.0f / Dd) - mean * mean;
  float rstd = rsqrtf(var + 1e-3f);
  float4 gg = ((const float4*)g)[t];
  float4 bb = ((const float4*)bia)[t];
  ushort4 o;
  o.x = f2bf((v.x - mean) * rstd * gg.x + bb.x);
  o.y = f2bf((v.y - mean) * rstd * gg.y + bb.y);
  o.z = f2bf((v.z - mean) * rstd * gg.z + bb.z);
  o.w = f2bf((v.w - mean) * rstd * gg.w + bb.w);
  *((ushort4*)(out + (long)row * Dd + t * 4)) = o;
}

// ---- prep: present emission (from c) + kp16 (past K bf16) + vT past columns ----
__global__ __launch_bounds__(256) void prep_kernel(const unsigned short* __restrict__ c,
                                                   const float* __restrict__ past,
                                                   float* __restrict__ present,
                                                   unsigned short* __restrict__ kp16,
                                                   unsigned short* __restrict__ vT) {
  long bid = blockIdx.x;
  if (bid < 16384) {
    long i = bid * 256 + threadIdx.x;
    int dh = (int)(i & 63);
    int s = (int)((i >> 6) & 2047);
    int h = (int)((i >> 17) & 15);
    int b = (int)(i >> 21);
    long crow = ((long)b * Ss + s) * (3 * Dd) + h * DHh + dh;
    unsigned short kv = c[crow + Dd];
    unsigned short vv = c[crow + 2 * Dd];
    present[((((long)b * 2 + 0) * Hh + h) * Ss + s) * DHh + dh] = bf2f(kv);
    present[((((long)b * 2 + 1) * Hh + h) * Ss + s) * DHh + dh] = bf2f(vv);
  } else if (bid < 17408) {
    long j = (bid - 16384) * 256 + threadIdx.x;
    int dh = (int)(j & 63);
    int p = (int)((j >> 6) & 127);
    int z = (int)(j >> 13);
    int b = z >> 4, h = z & 15;
    float pk = past[((((long)b * 2 + 0) * Hh + h) * Pp + p) * DHh + dh];
    kp16[((long)z * Pp + p) * DHh + dh] = f2bf(pk);
  } else {
    long j = (bid - 17408) * 256 + threadIdx.x;
    int p = (int)(j & 127);
    int dh = (int)((j >> 7) & 63);
    int z = (int)(j >> 13);
    int b = z >> 4, h = z & 15;
    float pv = past[((((long)b * 2 + 1) * Hh + h) * Pp + p) * DHh + dh];
    vT[((long)z * DHh + dh) * NS + p] = f2bf(pv);
  }
}

// ---------------- V transpose from c: fills vT cols [128, NS) ----------------
__global__ __launch_bounds__(256) void vtr_kernel(const unsigned short* __restrict__ c,
                                                  unsigned short* __restrict__ vT) {
  __shared__ unsigned short Tl[64 * 72];
  int z = blockIdx.y;
  int b = z >> 4, h = z & 15;
  int s0 = Pp + blockIdx.x * 64;
  int t = threadIdx.x;
#pragma unroll
  for (int it = 0; it < 2; it++) {
    int idx = t + it * 256, row = idx >> 3, c8 = (idx & 7) * 8;
    *(short8*)&Tl[row * 72 + c8] =
        *(const short8*)(c + ((long)b * Ss + s0 - Pp + row) * (3 * Dd) + 2 * Dd + h * DHh + c8);
  }
  __syncthreads();
#pragma unroll
  for (int it = 0; it < 2; it++) {
    int idx = t + it * 256, row = idx >> 3, c8 = (idx & 7) * 8;
    short8 g;
#pragma unroll
    for (int e = 0; e < 8; e++) g[e] = (short)Tl[(c8 + e) * 72 + row];
    *(short8*)(vT + ((long)z * DHh + row) * NS + s0 + c8) = g;
  }
}

// ---- fused attention (round-8 two-pass); Q/K sourced from c + kp16 ----
__global__ __launch_bounds__(256) void attn_kernel(const unsigned short* __restrict__ c,
                                                   const unsigned short* __restrict__ kp16,
                                                   const unsigned short* __restrict__ vTg,
                                                   float* __restrict__ wg,
                                                   unsigned short* __restrict__ am) {
  __shared__ unsigned short KV[128 * 72];
  __shared__ unsigned short Pl[128 * 136];
  int wgs = (blockIdx.x & 7) * 64 + (blockIdx.x >> 3);
  int z = wgs >> 4;
  int bx = 15 - (wgs & 15);
  int q0 = bx * 128;
  int bq = z >> 4, hh = z & 15;
  int t = threadIdx.x, lane = t & 63, wid = t >> 6;
  int lr = lane & 15, kgp = lane >> 4;
  const unsigned short* cb = c + (long)bq * Ss * (3 * Dd) + hh * DHh;
  const unsigned short* kp = kp16 + (long)z * Pp * DHh;
  const unsigned short* vz = vTg + (long)z * DHh * NS;
  float* wz = wg + (long)z * Ss * NS;

  short8 qa[2][2];
#pragma unroll
  for (int i = 0; i < 2; i++)
#pragma unroll
    for (int kk = 0; kk < 2; kk++)
      qa[i][kk] = *(const short8*)(cb + (long)(q0 + wid * 32 + i * 16 + lr) * (3 * Dd) +
                                   kk * 32 + kgp * 8);

  const int nt = bx + 2;
  float l_run[2][4] = {};

#define STAGE_K(kt_)                                                                   \
  do {                                                                                 \
    if ((kt_) == 0) {                                                                  \
      _Pragma("unroll") for (int it = 0; it < 4; it++) {                               \
        int idx = t + it * 256, row = idx >> 3, c8 = (idx & 7) * 8;                    \
        *(short8*)&KV[row * 72 + c8] = *(const short8*)(kp + (long)row * DHh + c8);    \
      }                                                                                \
    } else {                                                                           \
      _Pragma("unroll") for (int it = 0; it < 4; it++) {                               \
        int idx = t + it * 256, row = idx >> 3, c8 = (idx & 7) * 8;                    \
        *(short8*)&KV[row * 72 + c8] = *(const short8*)(                               \
            cb + (long)(((kt_)-1) * 128 + row) * (3 * Dd) + Dd + c8);                  \
      }                                                                                \
    }                                                                                  \
  } while (0)

  for (int kt = 0; kt < nt; kt++) {
    STAGE_K(kt);
    SYNC_LDS();
    floatx4 acc[2][8] = {};
    __builtin_amdgcn_s_setprio(1);
#pragma unroll
    for (int j = 0; j < 8; j++) {
      short8 b0 = *(const short8*)&KV[(j * 16 + lr) * 72 + kgp * 8];
      short8 b1 = *(const short8*)&KV[(j * 16 + lr) * 72 + 32 + kgp * 8];
#pragma unroll
      for (int i = 0; i < 2; i++) {
        acc[i][j] = __builtin_amdgcn_mfma_f32_16x16x32_bf16(qa[i][0], b0, acc[i][j], 0, 0, 0);
        acc[i][j] = __builtin_amdgcn_mfma_f32_16x16x32_bf16(qa[i][1], b1, acc[i][j], 0, 0, 0);
      }
    }
    __builtin_amdgcn_s_setprio(0);
#pragma unroll
    for (int i = 0; i < 2; i++) {
#pragma unroll
      for (int r = 0; r < 4; r++) {
        int row = q0 + wid * 32 + i * 16 + kgp * 4 + r;
        float su = 0.f;
#pragma unroll
        for (int j = 0; j < 8; j++) {
          int col = kt * 128 + j * 16 + lr;
          su += (col > row + Pp) ? 0.f : __expf(acc[i][j][r] * 0.125f - 8.0f);
        }
        su += __shfl_xor(su, 1);
        su += __shfl_xor(su, 2);
        su += __shfl_xor(su, 4);
        su += __shfl_xor(su, 8);
        l_run[i][r] += su;
      }
    }
    SYNC_LDS();
  }

  float cc[2][4];
#pragma unroll
  for (int i = 0; i < 2; i++)
#pragma unroll
    for (int r = 0; r < 4; r++) cc[i][r] = 8.0f + __logf(l_run[i][r]);

  floatx4 oacc[2][4] = {};
  for (int kt = 0; kt < nt; kt++) {
    STAGE_K(kt);
    SYNC_LDS();
    floatx4 acc[2][8] = {};
    __builtin_amdgcn_s_setprio(1);
#pragma unroll
    for (int j = 0; j < 8; j++) {
      short8 b0 = *(const short8*)&KV[(j * 16 + lr) * 72 + kgp * 8];
      short8 b1 = *(const short8*)&KV[(j * 16 + lr) * 72 + 32 + kgp * 8];
#pragma unroll
      for (int i = 0; i < 2; i++) {
        acc[i][j] = __builtin_amdgcn_mfma_f32_16x16x32_bf16(qa[i][0], b0, acc[i][j], 0, 0, 0);
        acc[i][j] = __builtin_amdgcn_mfma_f32_16x16x32_bf16(qa[i][1], b1, acc[i][j], 0, 0, 0);
      }
    }
    __builtin_amdgcn_s_setprio(0);
#pragma unroll
    for (int i = 0; i < 2; i++) {
#pragma unroll
      for (int r = 0; r < 4; r++) {
        int row = q0 + wid * 32 + i * 16 + kgp * 4 + r;
#pragma unroll
        for (int j = 0; j < 8; j++) {
          int col = kt * 128 + j * 16 + lr;
          float p = (col > row + Pp) ? 0.f : __expf(acc[i][j][r] * 0.125f - cc[i][r]);
          Pl[(wid * 32 + i * 16 + kgp * 4 + r) * 136 + j * 16 + lr] = f2bf(p);
        }
      }
    }
    SYNC_LDS();
#pragma unroll
    for (int it = 0; it < 4; it++) {
      int idx = t + it * 256, row = idx >> 4, c8 = (idx & 15) * 8;
      *(short8*)&KV[row * 136 + c8] = *(const short8*)(vz + (long)row * NS + kt * 128 + c8);
    }
    {
      int prow = t >> 5, pcol = (t & 31) * 4;
#pragma unroll
      for (int it = 0; it < 16; it++) {
        int row = it * 8 + prow;
        float4 f;
        f.x = bf2f(Pl[row * 136 + pcol]);
        f.y = bf2f(Pl[row * 136 + pcol + 1]);
        f.z = bf2f(Pl[row * 136 + pcol + 2]);
        f.w = bf2f(Pl[row * 136 + pcol + 3]);
        *(float4*)&wz[(long)(q0 + row) * NS + kt * 128 + pcol] = f;
      }
    }
    SYNC_LDS();
    __builtin_amdgcn_s_setprio(1);
#pragma unroll
    for (int kk = 0; kk < 4; kk++) {
      short8 pa[2];
#pragma unroll
      for (int i = 0; i < 2; i++)
        pa[i] = *(const short8*)&Pl[(wid * 32 + i * 16 + lr) * 136 + kk * 32 + kgp * 8];
#pragma unroll
      for (int jd = 0; jd < 4; jd++) {
        short8 bv = *(const short8*)&KV[(jd * 16 + lr) * 136 + kk * 32 + kgp * 8];
#pragma unroll
        for (int i = 0; i < 2; i++)
          oacc[i][jd] = __builtin_amdgcn_mfma_f32_16x16x32_bf16(pa[i], bv, oacc[i][jd], 0, 0, 0);
      }
    }
    __builtin_amdgcn_s_setprio(0);
    SYNC_LDS();
  }
#undef STAGE_K

  int zc0 = nt * 128;
  if (zc0 < NS) {
    for (int rr = 0; rr < 32; rr++) {
      int row = q0 + wid * 32 + rr;
      for (int cix = zc0 + (lane << 2); cix < NS; cix += 256) {
        float4 z4 = {0.f, 0.f, 0.f, 0.f};
        *(float4*)&wz[(long)row * NS + cix] = z4;
      }
    }
  }

#pragma unroll
  for (int i = 0; i < 2; i++)
#pragma unroll
    for (int jd = 0; jd < 4; jd++)
#pragma unroll
      for (int r = 0; r < 4; r++) {
        long row = (long)bq * Ss + q0 + wid * 32 + i * 16 + kgp * 4 + r;
        int col = hh * 64 + jd * 16 + lr;
        am[row * Dd + col] = f2bf(oacc[i][jd][r]);
      }
}

enum { EPI_BF16_BIAS = 0, EPI_RES = 3, EPI_GELU = 4 };

DEVI void epilogue_one(int EPIv, void* outv, const float* bias, const float* res,
                       int N, int mm, int nn, float v) {
  if (EPIv == EPI_BF16_BIAS) {
    ((unsigned short*)outv)[(long)mm * N + nn] = f2bf(v + bias[nn]);
  } else if (EPIv == EPI_RES) {
    ((float*)outv)[(long)mm * N + nn] = v + bias[nn] + res[(long)mm * N + nn];
  } else {
    float xv = v + bias[nn];
    float u = xv + 0.044715f * xv * xv * xv;
    float tv = 1.0f - 2.0f / (__expf(1.5957691216057308f * u) + 1.0f);
    ((unsigned short*)outv)[(long)mm * N + nn] = f2bf(0.5f * xv * (1.0f + tv));
  }
}

// --- 128-class bf16 MFMA GEMM (2-phase dbuf) for merge / MLP2 ---
template <int EPI, int BM, int BN, int NB>
__global__ __launch_bounds__(256) void gemm_k(const unsigned short* __restrict__ A16,
                                              const unsigned short* __restrict__ Bt,
                                              const float* __restrict__ bias,
                                              const float* __restrict__ res,
                                              void* __restrict__ outv,
                                              int M, int N, int K, int nwg) {
  constexpr int WTM = BM / 2, WTN = BN / 2;
  constexpr int FM = WTM / 16, FN = WTN / 16;
  constexpr int IA = BM / 64, IB = BN / 64;
  __shared__ unsigned short Alds[2][BM * 32];
  __shared__ unsigned short Blds[2][BN * 32];
  int cpx = nwg >> 3;
  int wgid = (blockIdx.x & 7) * cpx + (blockIdx.x >> 3);
  int mb = wgid / NB, nb = wgid % NB;
  int m0 = mb * BM, n0 = nb * BN;
  int t = threadIdx.x;
  int lane = t & 63, wid = t >> 6;
  int wm = wid >> 1, wn = wid & 1;
  floatx4 acc[FM][FN] = {};
  int lr = lane & 15, kg = lane >> 4;

  int srow = lane >> 2, skc = (lane & 3) * 8;
  const unsigned short* Ab = A16 + (long)(m0 + wid * (BM / 4) + srow) * K + skc;
  const unsigned short* Bp = Bt + (long)(n0 + wid * (BN / 4) + srow) * K + skc;
  long rstride = (long)16 * K;

#define STAGE(bb, k0)                                                         \
  do {                                                                        \
    _Pragma("unroll") for (int ii = 0; ii < IA; ii++)                         \
        gl_lds16(Ab + ii * rstride + (k0),                                    \
                 &Alds[bb][(wid * (BM / 4) + ii * 16) * 32]);                 \
    _Pragma("unroll") for (int ii = 0; ii < IB; ii++)                         \
        gl_lds16(Bp + ii * rstride + (k0),                                    \
                 &Blds[bb][(wid * (BN / 4) + ii * 16) * 32]);                 \
  } while (0)

  STAGE(0, 0);
  SYNC_VM();
  int cur = 0;
  int nt = K >> 5;
  for (int tt = 0; tt < nt; tt++) {
    if (tt + 1 < nt) STAGE(cur ^ 1, (tt + 1) * 32);
    short8 a[FM], b[FN];
#pragma unroll
    for (int i = 0; i < FM; i++)
      a[i] = *(const short8*)&Alds[cur][(wm * WTM + i * 16 + lr) * 32 + kg * 8];
#pragma unroll
    for (int j = 0; j < FN; j++)
      b[j] = *(const short8*)&Blds[cur][(wn * WTN + j * 16 + lr) * 32 + kg * 8];
    __builtin_amdgcn_s_setprio(1);
#pragma unroll
    for (int i = 0; i < FM; i++)
#pragma unroll
      for (int j = 0; j < FN; j++)
        acc[i][j] = __builtin_amdgcn_mfma_f32_16x16x32_bf16(a[i], b[j], acc[i][j], 0, 0, 0);
    __builtin_amdgcn_s_setprio(0);
    SYNC_VM();
    cur ^= 1;
  }
#undef STAGE

#pragma unroll
  for (int i = 0; i < FM; i++)
#pragma unroll
    for (int j = 0; j < FN; j++)
#pragma unroll
      for (int r = 0; r < 4; r++)
        epilogue_one(EPI, outv, bias, res, N,
                     m0 + wm * WTM + i * 16 + kg * 4 + r,
                     n0 + wn * WTN + j * 16 + lr, acc[i][j][r]);
}

// --- 256x256 8-phase GEMM (T3+T4): BK=64, 512 thr (2Mx4N waves), LDS 128KB dbuf ---
template <int EPI, int NB>
__global__ __launch_bounds__(512) void gemm256_k(const unsigned short* __restrict__ A16,
                                                 const unsigned short* __restrict__ Bt,
                                                 const float* __restrict__ bias,
                                                 const float* __restrict__ res,
                                                 void* __restrict__ outv,
                                                 int M, int N, int K, int nwg) {
  __shared__ unsigned short Al[2][256 * 64];
  __shared__ unsigned short Bl[2][256 * 64];
  int cpx = nwg >> 3;
  int wgid = (blockIdx.x & 7) * cpx + (blockIdx.x >> 3);
  int mb = wgid / NB, nb = wgid % NB;
  int m0 = mb * 256, n0 = nb * 256;
  int tid = threadIdx.x;
  int lane = tid & 63, w = tid >> 6;
  int wm = w >> 2, wn = w & 3; // 2M x 4N
  int lr = lane & 15, kg = lane >> 4;
  floatx4 acc[8][4] = {};

  // staging: issue ii covers rows ii*64..ii*64+63; thread -> row=ii*64+(tid>>3), col8=(tid&7)*8
  int srow = tid >> 3;
  int scol = (tid & 7) * 8;
  const unsigned short* Abase = A16 + (long)(m0 + srow) * K + scol;
  const unsigned short* Bbase = Bt + (long)(n0 + srow) * K + scol;
  long rstride64 = (long)64 * K;
  int ldst = w * 512; // wave-uniform element base within an 8KB issue-chunk (+lane*16B by HW)

#define STAGE4(bb, k0, half)                                                       \
  do {                                                                             \
    _Pragma("unroll") for (int ii = 0; ii < 2; ii++) {                             \
      int i4 = (half) * 2 + ii;                                                    \
      gl_lds16(Abase + i4 * rstride64 + (k0), &Al[bb][i4 * 4096 + ldst]);          \
      gl_lds16(Bbase + i4 * rstride64 + (k0), &Bl[bb][i4 * 4096 + ldst]);          \
    }                                                                              \
  } while (0)

  STAGE4(0, 0, 0);
  STAGE4(0, 0, 1);
  int cur = 0;
  int nt = K >> 6;
  for (int t = 0; t < nt; t++) {
    // tile t DMA landed (own waits) + all waves done reading buffer being re-staged
    asm volatile("s_waitcnt vmcnt(0)" ::: "memory");
    __builtin_amdgcn_s_barrier();
    const unsigned short* Ac = &Al[cur][0];
    const unsigned short* Bc = &Bl[cur][0];
    short8 bf[4][2];
#pragma unroll
    for (int p = 0; p < 4; p++) {
      // ds-read this quadrant's A fragments
      short8 af[2][2];
#pragma unroll
      for (int q = 0; q < 2; q++)
#pragma unroll
        for (int kk = 0; kk < 2; kk++)
          af[q][kk] =
              *(const short8*)&Ac[(wm * 128 + (p * 2 + q) * 16 + lr) * 64 + kk * 32 + kg * 8];
      if (p == 0) {
#pragma unroll
        for (int fn = 0; fn < 4; fn++)
#pragma unroll
          for (int kk = 0; kk < 2; kk++)
            bf[fn][kk] = *(const short8*)&Bc[(wn * 64 + fn * 16 + lr) * 64 + kk * 32 + kg * 8];
      }
      // front-loaded staging of tile t+1 into the other buffer (no LDS hazard: DMA->nxt)
      if (t + 1 < nt) {
        if (p == 0) STAGE4(cur ^ 1, (t + 1) * 64, 0);
        if (p == 1) STAGE4(cur ^ 1, (t + 1) * 64, 1);
      }
      __builtin_amdgcn_s_barrier(); // phase alignment
      asm volatile("s_waitcnt lgkmcnt(0)" ::: "memory");
      __builtin_amdgcn_s_setprio(1);
#pragma unroll
      for (int q = 0; q < 2; q++)
#pragma unroll
        for (int fn = 0; fn < 4; fn++)
#pragma unroll
          for (int kk = 0; kk < 2; kk++)
            acc[p * 2 + q][fn] = __builtin_amdgcn_mfma_f32_16x16x32_bf16(
                af[q][kk], bf[fn][kk], acc[p * 2 + q][fn], 0, 0, 0);
      __builtin_amdgcn_s_setprio(0);
      __builtin_amdgcn_s_barrier();
    }
    cur ^= 1;
  }
#undef STAGE4

#pragma unroll
  for (int fm = 0; fm < 8; fm++)
#pragma unroll
    for (int fn = 0; fn < 4; fn++)
#pragma unroll
      for (int r = 0; r < 4; r++)
        epilogue_one(EPI, outv, bias, res, N,
                     m0 + wm * 128 + fm * 16 + kg * 4 + r,
                     n0 + wn * 64 + fn * 16 + lr, acc[fm][fn][r]);
}

extern "C" void kernel_launch(void* const* d_in, const int* in_sizes, int n_in,
                              void* d_out, int out_size, void* d_ws, size_t ws_size,
                              hipStream_t stream) {
  (void)in_sizes; (void)n_in; (void)out_size; (void)ws_size;
  const float* x = (const float*)d_in[0];
  const float* past = (const float*)d_in[1];
  const float* qkv_w = (const float*)d_in[2];
  const float* qkv_b = (const float*)d_in[3];
  const float* merge_w = (const float*)d_in[4];
  const float* merge_b = (const float*)d_in[5];
  const float* ln1_w = (const float*)d_in[6];
  const float* ln1_b = (const float*)d_in[7];
  const float* ln2_w = (const float*)d_in[8];
  const float* ln2_b = (const float*)d_in[9];
  const float* g1 = (const float*)d_in[10];
  const float* b1 = (const float*)d_in[11];
  const float* g2 = (const float*)d_in[12];
  const float* b2 = (const float*)d_in[13];

  char* ws = (char*)d_ws;
  unsigned short* qkv_wT = (unsigned short*)(ws + 0);
  unsigned short* merge_wT = (unsigned short*)(ws + 6291456);
  unsigned short* ln1_wT = (unsigned short*)(ws + 8388608);
  unsigned short* ln2_wT = (unsigned short*)(ws + 16777216);
  unsigned short* h = (unsigned short*)(ws + 25165824);
  unsigned short* am = (unsigned short*)(ws + 33554432);
  unsigned short* kp16 = (unsigned short*)(ws + 41943040);
  unsigned short* vT = (unsigned short*)(ws + 50855936);
  unsigned short* c = (unsigned short*)(ws + 59768832);
  unsigned short* m1 = (unsigned short*)(ws + 25165824);
  float* xa = (float*)(ws + 68157440);
  unsigned short* h2 = (unsigned short*)(ws + 84934656);

  float* xm_out = (float*)d_out;
  float* present = ((float*)d_out) + (long)Bb * Ss * Dd;
  float* w_out = present + (long)Bb * 2 * Hh * Ss * DHh;

  wt_cvt_all_kernel<<<12288, 256, 0, stream>>>(qkv_w, merge_w, ln1_w, ln2_w,
                                               qkv_wT, merge_wT, ln1_wT, ln2_wT);

  ln_kernel<<<Bb * Ss, 256, 0, stream>>>(x, g1, b1, h);

  // c = LN(x) @ qkv_w + qkv_b  (256^2 8-phase, 192 blocks)
  gemm256_k<EPI_BF16_BIAS, 12><<<192, 512, 0, stream>>>(
      h, qkv_wT, qkv_b, nullptr, c, 4096, 3072, 1024, 192);

  prep_kernel<<<18432, 256, 0, stream>>>(c, past, present, kp16, vT);

  vtr_kernel<<<dim3(Ss / 64, Bb * Hh), 256, 0, stream>>>(c, vT);

  attn_kernel<<<512, 256, 0, stream>>>(c, kp16, vT, w_out, am);

  gemm_k<EPI_RES, 64, 128, 8><<<64 * 8, 256, 0, stream>>>(
      am, merge_wT, merge_b, x, xa, 4096, 1024, 1024, 64 * 8);

  ln_kernel<<<Bb * Ss, 256, 0, stream>>>(xa, g2, b2, h2);

  // m1 = gelu(h2 @ ln1_w + ln1_b)  (256^2 8-phase, 256 blocks = 1/CU)
  gemm256_k<EPI_GELU, 16><<<256, 512, 0, stream>>>(
      h2, ln1_wT, ln1_b, nullptr, m1, 4096, 4096, 1024, 256);

  gemm_k<EPI_RES, 64, 128, 8><<<64 * 8, 256, 0, stream>>>(
      m1, ln2_wT, ln2_b, x, xm_out, 4096, 1024, 4096, 64 * 8);
}

// Round 13
// 421.115 us; speedup vs baseline: 1.0251x; 1.0251x over previous
//
#include <hip/hip_runtime.h>

typedef __attribute__((ext_vector_type(8))) short short8;
typedef __attribute__((ext_vector_type(4))) float floatx4;

constexpr int Bb = 2, Ss = 2048, Dd = 1024, Hh = 16, Pp = 128, DHh = 64;
constexpr int NS = Ss + Pp; // 2176

#define DEVI __device__ __forceinline__

#define SYNC_LDS()                                          \
  do {                                                      \
    asm volatile("s_waitcnt lgkmcnt(0)" ::: "memory");      \
    __builtin_amdgcn_s_barrier();                           \
  } while (0)
#define SYNC_VM()                                           \
  do {                                                      \
    asm volatile("s_waitcnt vmcnt(0)" ::: "memory");        \
    __builtin_amdgcn_s_barrier();                           \
  } while (0)

DEVI unsigned short f2bf(float f) {
  unsigned u = __float_as_uint(f);
  u += 0x7fffu + ((u >> 16) & 1u);
  return (unsigned short)(u >> 16);
}
DEVI float bf2f(unsigned short h) { return __uint_as_float(((unsigned)h) << 16); }

DEVI void gl_lds16(const unsigned short* g, unsigned short* l) {
  __builtin_amdgcn_global_load_lds((const __attribute__((address_space(1))) unsigned int*)g,
                                   (__attribute__((address_space(3))) unsigned int*)l, 16, 0, 0);
}

// ------- fused weight transpose + f32->bf16 for all 4 weights, one launch -------
__global__ __launch_bounds__(256) void wt_cvt_all_kernel(const float* __restrict__ qkv_w,
                                                         const float* __restrict__ merge_w,
                                                         const float* __restrict__ ln1_w,
                                                         const float* __restrict__ ln2_w,
                                                         unsigned short* __restrict__ qkv_wT,
                                                         unsigned short* __restrict__ merge_wT,
                                                         unsigned short* __restrict__ ln1_wT,
                                                         unsigned short* __restrict__ ln2_wT) {
  __shared__ float tl[32][33];
  int bid = blockIdx.x;
  const float* W;
  unsigned short* Wt;
  int K, N, bx, by;
  if (bid < 3072) {
    W = qkv_w; Wt = qkv_wT; K = 1024; N = 3072; bx = bid % 96; by = bid / 96;
  } else if (bid < 4096) {
    int b2 = bid - 3072; W = merge_w; Wt = merge_wT; K = 1024; N = 1024; bx = b2 % 32; by = b2 / 32;
  } else if (bid < 8192) {
    int b3 = bid - 4096; W = ln1_w; Wt = ln1_wT; K = 1024; N = 4096; bx = b3 % 128; by = b3 / 128;
  } else {
    int b4 = bid - 8192; W = ln2_w; Wt = ln2_wT; K = 4096; N = 1024; bx = b4 % 32; by = b4 / 32;
  }
  int n0 = bx * 32, k0 = by * 32;
  int tx = threadIdx.x & 31, ty = threadIdx.x >> 5;
#pragma unroll
  for (int j = 0; j < 4; j++)
    tl[ty + 8 * j][tx] = W[(long)(k0 + ty + 8 * j) * N + n0 + tx];
  __syncthreads();
#pragma unroll
  for (int j = 0; j < 4; j++)
    Wt[(long)(n0 + ty + 8 * j) * K + k0 + tx] = f2bf(tl[tx][ty + 8 * j]);
}

// ---------------- layernorm ----------------
__global__ __launch_bounds__(256) void ln_kernel(const float* __restrict__ x,
                                                 const float* __restrict__ g,
                                                 const float* __restrict__ bia,
                                                 unsigned short* __restrict__ out) {
  int row = blockIdx.x;
  int t = threadIdx.x;
  const float4* xr = (const float4*)(x + (long)row * Dd);
  float4 v = xr[t];
  float s1 = v.x + v.y + v.z + v.w;
  float s2 = v.x * v.x + v.y * v.y + v.z * v.z + v.w * v.w;
#pragma unroll
  for (int o = 1; o < 64; o <<= 1) {
    s1 += __shfl_xor(s1, o);
    s2 += __shfl_xor(s2, o);
  }
  __shared__ float r1[4], r2[4];
  int wid = t >> 6;
  if ((t & 63) == 0) { r1[wid] = s1; r2[wid] = s2; }
  __syncthreads();
  s1 = r1[0] + r1[1] + r1[2] + r1[3];
  s2 = r2[0] + r2[1] + r2[2] + r2[3];
  float mean = s1 * (1.0f / Dd);
  float var = s2 * (1.0f / Dd) - mean * mean;
  float rstd = rsqrtf(var + 1e-3f);
  float4 gg = ((const float4*)g)[t];
  float4 bb = ((const float4*)bia)[t];
  ushort4 o;
  o.x = f2bf((v.x - mean) * rstd * gg.x + bb.x);
  o.y = f2bf((v.y - mean) * rstd * gg.y + bb.y);
  o.z = f2bf((v.z - mean) * rstd * gg.z + bb.z);
  o.w = f2bf((v.w - mean) * rstd * gg.w + bb.w);
  *((ushort4*)(out + (long)row * Dd + t * 4)) = o;
}

// ---- prep: present (from c) + kp16 (past K) + vT past cols + vT new cols (fused vtr) ----
// blocks [0,16384): present; [16384,17408): kp16; [17408,18432): vT past;
// blocks [18432,19456): vT new columns via LDS transpose from c's V section
__global__ __launch_bounds__(256) void prep_kernel(const unsigned short* __restrict__ c,
                                                   const float* __restrict__ past,
                                                   float* __restrict__ present,
                                                   unsigned short* __restrict__ kp16,
                                                   unsigned short* __restrict__ vT) {
  __shared__ unsigned short Tl[64 * 72];
  long bid = blockIdx.x;
  if (bid < 16384) {
    long i = bid * 256 + threadIdx.x;
    int dh = (int)(i & 63);
    int s = (int)((i >> 6) & 2047);
    int h = (int)((i >> 17) & 15);
    int b = (int)(i >> 21);
    long crow = ((long)b * Ss + s) * (3 * Dd) + h * DHh + dh;
    unsigned short kv = c[crow + Dd];
    unsigned short vv = c[crow + 2 * Dd];
    present[((((long)b * 2 + 0) * Hh + h) * Ss + s) * DHh + dh] = bf2f(kv);
    present[((((long)b * 2 + 1) * Hh + h) * Ss + s) * DHh + dh] = bf2f(vv);
  } else if (bid < 17408) {
    long j = (bid - 16384) * 256 + threadIdx.x;
    int dh = (int)(j & 63);
    int p = (int)((j >> 6) & 127);
    int z = (int)(j >> 13);
    int b = z >> 4, h = z & 15;
    float pk = past[((((long)b * 2 + 0) * Hh + h) * Pp + p) * DHh + dh];
    kp16[((long)z * Pp + p) * DHh + dh] = f2bf(pk);
  } else if (bid < 18432) {
    long j = (bid - 17408) * 256 + threadIdx.x;
    int p = (int)(j & 127);
    int dh = (int)((j >> 7) & 63);
    int z = (int)(j >> 13);
    int b = z >> 4, h = z & 15;
    float pv = past[((((long)b * 2 + 1) * Hh + h) * Pp + p) * DHh + dh];
    vT[((long)z * DHh + dh) * NS + p] = f2bf(pv);
  } else {
    // fused vtr: 1024 blocks, 32 s-tiles x 32 z
    int bid2 = (int)(bid - 18432);
    int z = bid2 >> 5;
    int b = z >> 4, h = z & 15;
    int s0 = Pp + (bid2 & 31) * 64;
    int t = threadIdx.x;
#pragma unroll
    for (int it = 0; it < 2; it++) {
      int idx = t + it * 256, row = idx >> 3, c8 = (idx & 7) * 8;
      *(short8*)&Tl[row * 72 + c8] =
          *(const short8*)(c + ((long)b * Ss + s0 - Pp + row) * (3 * Dd) + 2 * Dd + h * DHh + c8);
    }
    __syncthreads();
#pragma unroll
    for (int it = 0; it < 2; it++) {
      int idx = t + it * 256, row = idx >> 3, c8 = (idx & 7) * 8;
      short8 g;
#pragma unroll
      for (int e = 0; e < 8; e++) g[e] = (short)Tl[(c8 + e) * 72 + row];
      *(short8*)(vT + ((long)z * DHh + row) * NS + s0 + c8) = g;
    }
  }
}

// ---- fused attention (two-pass, fixed-max softmax); Q/K sourced from c + kp16 ----
// grid 512, 256 threads (4 waves x 32 rows)
__global__ __launch_bounds__(256) void attn_kernel(const unsigned short* __restrict__ c,
                                                   const unsigned short* __restrict__ kp16,
                                                   const unsigned short* __restrict__ vTg,
                                                   float* __restrict__ wg,
                                                   unsigned short* __restrict__ am) {
  __shared__ unsigned short KV[128 * 72];
  __shared__ unsigned short Pl[128 * 136];
  int wgs = (blockIdx.x & 7) * 64 + (blockIdx.x >> 3);
  int z = wgs >> 4;
  int bx = 15 - (wgs & 15);
  int q0 = bx * 128;
  int bq = z >> 4, hh = z & 15;
  int t = threadIdx.x, lane = t & 63, wid = t >> 6;
  int lr = lane & 15, kgp = lane >> 4;
  const unsigned short* cb = c + (long)bq * Ss * (3 * Dd) + hh * DHh;
  const unsigned short* kp = kp16 + (long)z * Pp * DHh;
  const unsigned short* vz = vTg + (long)z * DHh * NS;
  float* wz = wg + (long)z * Ss * NS;

  short8 qa[2][2];
#pragma unroll
  for (int i = 0; i < 2; i++)
#pragma unroll
    for (int kk = 0; kk < 2; kk++)
      qa[i][kk] = *(const short8*)(cb + (long)(q0 + wid * 32 + i * 16 + lr) * (3 * Dd) +
                                   kk * 32 + kgp * 8);

  const int nt = bx + 2;
  float l_run[2][4] = {};

#define STAGE_K(kt_)                                                                   \
  do {                                                                                 \
    if ((kt_) == 0) {                                                                  \
      _Pragma("unroll") for (int it = 0; it < 4; it++) {                               \
        int idx = t + it * 256, row = idx >> 3, c8 = (idx & 7) * 8;                    \
        *(short8*)&KV[row * 72 + c8] = *(const short8*)(kp + (long)row * DHh + c8);    \
      }                                                                                \
    } else {                                                                           \
      _Pragma("unroll") for (int it = 0; it < 4; it++) {                               \
        int idx = t + it * 256, row = idx >> 3, c8 = (idx & 7) * 8;                    \
        *(short8*)&KV[row * 72 + c8] = *(const short8*)(                               \
            cb + (long)(((kt_)-1) * 128 + row) * (3 * Dd) + Dd + c8);                  \
      }                                                                                \
    }                                                                                  \
  } while (0)

  // ---- pass 1: denominators (fixed max M0=8) ----
  for (int kt = 0; kt < nt; kt++) {
    STAGE_K(kt);
    SYNC_LDS();
    floatx4 acc[2][8] = {};
    __builtin_amdgcn_s_setprio(1);
#pragma unroll
    for (int j = 0; j < 8; j++) {
      short8 b0 = *(const short8*)&KV[(j * 16 + lr) * 72 + kgp * 8];
      short8 b1 = *(const short8*)&KV[(j * 16 + lr) * 72 + 32 + kgp * 8];
#pragma unroll
      for (int i = 0; i < 2; i++) {
        acc[i][j] = __builtin_amdgcn_mfma_f32_16x16x32_bf16(qa[i][0], b0, acc[i][j], 0, 0, 0);
        acc[i][j] = __builtin_amdgcn_mfma_f32_16x16x32_bf16(qa[i][1], b1, acc[i][j], 0, 0, 0);
      }
    }
    __builtin_amdgcn_s_setprio(0);
#pragma unroll
    for (int i = 0; i < 2; i++) {
#pragma unroll
      for (int r = 0; r < 4; r++) {
        int row = q0 + wid * 32 + i * 16 + kgp * 4 + r;
        float su = 0.f;
#pragma unroll
        for (int j = 0; j < 8; j++) {
          int col = kt * 128 + j * 16 + lr;
          su += (col > row + Pp) ? 0.f : __expf(acc[i][j][r] * 0.125f - 8.0f);
        }
        su += __shfl_xor(su, 1);
        su += __shfl_xor(su, 2);
        su += __shfl_xor(su, 4);
        su += __shfl_xor(su, 8);
        l_run[i][r] += su;
      }
    }
    SYNC_LDS();
  }

  float cc[2][4];
#pragma unroll
  for (int i = 0; i < 2; i++)
#pragma unroll
    for (int r = 0; r < 4; r++) cc[i][r] = 8.0f + __logf(l_run[i][r]);

  // ---- pass 2: w + PV ----
  floatx4 oacc[2][4] = {};
  for (int kt = 0; kt < nt; kt++) {
    STAGE_K(kt);
    SYNC_LDS();
    floatx4 acc[2][8] = {};
    __builtin_amdgcn_s_setprio(1);
#pragma unroll
    for (int j = 0; j < 8; j++) {
      short8 b0 = *(const short8*)&KV[(j * 16 + lr) * 72 + kgp * 8];
      short8 b1 = *(const short8*)&KV[(j * 16 + lr) * 72 + 32 + kgp * 8];
#pragma unroll
      for (int i = 0; i < 2; i++) {
        acc[i][j] = __builtin_amdgcn_mfma_f32_16x16x32_bf16(qa[i][0], b0, acc[i][j], 0, 0, 0);
        acc[i][j] = __builtin_amdgcn_mfma_f32_16x16x32_bf16(qa[i][1], b1, acc[i][j], 0, 0, 0);
      }
    }
    __builtin_amdgcn_s_setprio(0);
#pragma unroll
    for (int i = 0; i < 2; i++) {
#pragma unroll
      for (int r = 0; r < 4; r++) {
        int row = q0 + wid * 32 + i * 16 + kgp * 4 + r;
#pragma unroll
        for (int j = 0; j < 8; j++) {
          int col = kt * 128 + j * 16 + lr;
          float p = (col > row + Pp) ? 0.f : __expf(acc[i][j][r] * 0.125f - cc[i][r]);
          Pl[(wid * 32 + i * 16 + kgp * 4 + r) * 136 + j * 16 + lr] = f2bf(p);
        }
      }
    }
    SYNC_LDS(); // K readers done + Pl visible
#pragma unroll
    for (int it = 0; it < 4; it++) {
      int idx = t + it * 256, row = idx >> 4, c8 = (idx & 15) * 8;
      *(short8*)&KV[row * 136 + c8] = *(const short8*)(vz + (long)row * NS + kt * 128 + c8);
    }
    {
      int prow = t >> 5, pcol = (t & 31) * 4;
#pragma unroll
      for (int it = 0; it < 16; it++) {
        int row = it * 8 + prow;
        float4 f;
        f.x = bf2f(Pl[row * 136 + pcol]);
        f.y = bf2f(Pl[row * 136 + pcol + 1]);
        f.z = bf2f(Pl[row * 136 + pcol + 2]);
        f.w = bf2f(Pl[row * 136 + pcol + 3]);
        *(float4*)&wz[(long)(q0 + row) * NS + kt * 128 + pcol] = f;
      }
    }
    SYNC_LDS(); // V^T staged
    __builtin_amdgcn_s_setprio(1);
#pragma unroll
    for (int kk = 0; kk < 4; kk++) {
      short8 pa[2];
#pragma unroll
      for (int i = 0; i < 2; i++)
        pa[i] = *(const short8*)&Pl[(wid * 32 + i * 16 + lr) * 136 + kk * 32 + kgp * 8];
#pragma unroll
      for (int jd = 0; jd < 4; jd++) {
        short8 bv = *(const short8*)&KV[(jd * 16 + lr) * 136 + kk * 32 + kgp * 8];
#pragma unroll
        for (int i = 0; i < 2; i++)
          oacc[i][jd] = __builtin_amdgcn_mfma_f32_16x16x32_bf16(pa[i], bv, oacc[i][jd], 0, 0, 0);
      }
    }
    __builtin_amdgcn_s_setprio(0);
    SYNC_LDS(); // PV readers done before next K staging
  }
#undef STAGE_K

  int zc0 = nt * 128;
  if (zc0 < NS) {
    for (int rr = 0; rr < 32; rr++) {
      int row = q0 + wid * 32 + rr;
      for (int cix = zc0 + (lane << 2); cix < NS; cix += 256) {
        float4 z4 = {0.f, 0.f, 0.f, 0.f};
        *(float4*)&wz[(long)row * NS + cix] = z4;
      }
    }
  }

#pragma unroll
  for (int i = 0; i < 2; i++)
#pragma unroll
    for (int jd = 0; jd < 4; jd++)
#pragma unroll
      for (int r = 0; r < 4; r++) {
        long row = (long)bq * Ss + q0 + wid * 32 + i * 16 + kgp * 4 + r;
        int col = hh * 64 + jd * 16 + lr;
        am[row * Dd + col] = f2bf(oacc[i][jd][r]);
      }
}

// --- bf16 MFMA GEMM: m97 staging + 2-phase dbuf prefetch; tile size templated ---
enum { EPI_BF16_BIAS = 0, EPI_RES = 3, EPI_GELU = 4 };

template <int EPI, int BM, int BN, int NB>
__global__ __launch_bounds__(256) void gemm_k(const unsigned short* __restrict__ A16,
                                              const unsigned short* __restrict__ Bt,
                                              const float* __restrict__ bias,
                                              const float* __restrict__ res,
                                              void* __restrict__ outv,
                                              int M, int N, int K, int nwg) {
  constexpr int WTM = BM / 2, WTN = BN / 2;
  constexpr int FM = WTM / 16, FN = WTN / 16;
  constexpr int IA = BM / 64, IB = BN / 64;
  __shared__ unsigned short Alds[2][BM * 32];
  __shared__ unsigned short Blds[2][BN * 32];
  int cpx = nwg >> 3;
  int wgid = (blockIdx.x & 7) * cpx + (blockIdx.x >> 3);
  int mb = wgid / NB, nb = wgid % NB;
  int m0 = mb * BM, n0 = nb * BN;
  int t = threadIdx.x;
  int lane = t & 63, wid = t >> 6;
  int wm = wid >> 1, wn = wid & 1;
  floatx4 acc[FM][FN] = {};
  int lr = lane & 15, kg = lane >> 4;

  int srow = lane >> 2, skc = (lane & 3) * 8;
  const unsigned short* Ab = A16 + (long)(m0 + wid * (BM / 4) + srow) * K + skc;
  const unsigned short* Bp = Bt + (long)(n0 + wid * (BN / 4) + srow) * K + skc;
  long rstride = (long)16 * K;

#define STAGE(bb, k0)                                                         \
  do {                                                                        \
    _Pragma("unroll") for (int ii = 0; ii < IA; ii++)                         \
        gl_lds16(Ab + ii * rstride + (k0),                                    \
                 &Alds[bb][(wid * (BM / 4) + ii * 16) * 32]);                 \
    _Pragma("unroll") for (int ii = 0; ii < IB; ii++)                         \
        gl_lds16(Bp + ii * rstride + (k0),                                    \
                 &Blds[bb][(wid * (BN / 4) + ii * 16) * 32]);                 \
  } while (0)

  STAGE(0, 0);
  SYNC_VM();
  int cur = 0;
  int nt = K >> 5;
  for (int tt = 0; tt < nt; tt++) {
    if (tt + 1 < nt) STAGE(cur ^ 1, (tt + 1) * 32);
    short8 a[FM], b[FN];
#pragma unroll
    for (int i = 0; i < FM; i++)
      a[i] = *(const short8*)&Alds[cur][(wm * WTM + i * 16 + lr) * 32 + kg * 8];
#pragma unroll
    for (int j = 0; j < FN; j++)
      b[j] = *(const short8*)&Blds[cur][(wn * WTN + j * 16 + lr) * 32 + kg * 8];
    __builtin_amdgcn_s_setprio(1);
#pragma unroll
    for (int i = 0; i < FM; i++)
#pragma unroll
      for (int j = 0; j < FN; j++)
        acc[i][j] = __builtin_amdgcn_mfma_f32_16x16x32_bf16(a[i], b[j], acc[i][j], 0, 0, 0);
    __builtin_amdgcn_s_setprio(0);
    SYNC_VM();
    cur ^= 1;
  }
#undef STAGE

#pragma unroll
  for (int i = 0; i < FM; i++) {
#pragma unroll
    for (int j = 0; j < FN; j++) {
#pragma unroll
      for (int r = 0; r < 4; r++) {
        int mm = m0 + wm * WTM + i * 16 + kg * 4 + r;
        int nn = n0 + wn * WTN + j * 16 + lr;
        float v = acc[i][j][r];
        if constexpr (EPI == EPI_BF16_BIAS) {
          ((unsigned short*)outv)[(long)mm * N + nn] = f2bf(v + bias[nn]);
        } else if constexpr (EPI == EPI_RES) {
          ((float*)outv)[(long)mm * N + nn] = v + bias[nn] + res[(long)mm * N + nn];
        } else if constexpr (EPI == EPI_GELU) {
          float xv = v + bias[nn];
          float u = xv + 0.044715f * xv * xv * xv;
          float tv = 1.0f - 2.0f / (__expf(1.5957691216057308f * u) + 1.0f);
          ((unsigned short*)outv)[(long)mm * N + nn] = f2bf(0.5f * xv * (1.0f + tv));
        }
      }
    }
  }
}

extern "C" void kernel_launch(void* const* d_in, const int* in_sizes, int n_in,
                              void* d_out, int out_size, void* d_ws, size_t ws_size,
                              hipStream_t stream) {
  (void)in_sizes; (void)n_in; (void)out_size; (void)ws_size;
  const float* x = (const float*)d_in[0];
  const float* past = (const float*)d_in[1];
  const float* qkv_w = (const float*)d_in[2];
  const float* qkv_b = (const float*)d_in[3];
  const float* merge_w = (const float*)d_in[4];
  const float* merge_b = (const float*)d_in[5];
  const float* ln1_w = (const float*)d_in[6];
  const float* ln1_b = (const float*)d_in[7];
  const float* ln2_w = (const float*)d_in[8];
  const float* ln2_b = (const float*)d_in[9];
  const float* g1 = (const float*)d_in[10];
  const float* b1 = (const float*)d_in[11];
  const float* g2 = (const float*)d_in[12];
  const float* b2 = (const float*)d_in[13];

  char* ws = (char*)d_ws;
  unsigned short* qkv_wT = (unsigned short*)(ws + 0);
  unsigned short* merge_wT = (unsigned short*)(ws + 6291456);
  unsigned short* ln1_wT = (unsigned short*)(ws + 8388608);
  unsigned short* ln2_wT = (unsigned short*)(ws + 16777216);
  unsigned short* h = (unsigned short*)(ws + 25165824);
  unsigned short* am = (unsigned short*)(ws + 33554432);
  unsigned short* kp16 = (unsigned short*)(ws + 41943040);
  unsigned short* vT = (unsigned short*)(ws + 50855936);
  unsigned short* c = (unsigned short*)(ws + 59768832);
  unsigned short* m1 = (unsigned short*)(ws + 25165824);
  float* xa = (float*)(ws + 68157440);
  unsigned short* h2 = (unsigned short*)(ws + 84934656);

  float* xm_out = (float*)d_out;
  float* present = ((float*)d_out) + (long)Bb * Ss * Dd;
  float* w_out = present + (long)Bb * 2 * Hh * Ss * DHh;

  wt_cvt_all_kernel<<<12288, 256, 0, stream>>>(qkv_w, merge_w, ln1_w, ln2_w,
                                               qkv_wT, merge_wT, ln1_wT, ln2_wT);

  ln_kernel<<<Bb * Ss, 256, 0, stream>>>(x, g1, b1, h);

  // c = LN(x) @ qkv_w + qkv_b  (2-phase 128^2, 768 blocks = 3/CU)
  gemm_k<EPI_BF16_BIAS, 128, 128, 24><<<32 * 24, 256, 0, stream>>>(
      h, qkv_wT, qkv_b, nullptr, c, 4096, 3072, 1024, 32 * 24);

  // present + past-K bf16 + vT past cols + vT new cols (fused vtr)
  prep_kernel<<<19456, 256, 0, stream>>>(c, past, present, kp16, vT);

  attn_kernel<<<512, 256, 0, stream>>>(c, kp16, vT, w_out, am);

  gemm_k<EPI_RES, 64, 128, 8><<<64 * 8, 256, 0, stream>>>(
      am, merge_wT, merge_b, x, xa, 4096, 1024, 1024, 64 * 8);

  ln_kernel<<<Bb * Ss, 256, 0, stream>>>(xa, g2, b2, h2);

  gemm_k<EPI_GELU, 128, 128, 32><<<32 * 32, 256, 0, stream>>>(
      h2, ln1_wT, ln1_b, nullptr, m1, 4096, 4096, 1024, 32 * 32);

  gemm_k<EPI_RES, 64, 128, 8><<<64 * 8, 256, 0, stream>>>(
      m1, ln2_wT, ln2_b, x, xm_out, 4096, 1024, 4096, 64 * 8);
}

// Round 14
// 416.734 us; speedup vs baseline: 1.0359x; 1.0105x over previous
//
#include <hip/hip_runtime.h>

typedef __attribute__((ext_vector_type(8))) short short8;
typedef __attribute__((ext_vector_type(4))) float floatx4;

constexpr int Bb = 2, Ss = 2048, Dd = 1024, Hh = 16, Pp = 128, DHh = 64;
constexpr int NS = Ss + Pp; // 2176

#define DEVI __device__ __forceinline__

#define SYNC_LDS()                                          \
  do {                                                      \
    asm volatile("s_waitcnt lgkmcnt(0)" ::: "memory");      \
    __builtin_amdgcn_s_barrier();                           \
  } while (0)
#define SYNC_VM()                                           \
  do {                                                      \
    asm volatile("s_waitcnt vmcnt(0)" ::: "memory");        \
    __builtin_amdgcn_s_barrier();                           \
  } while (0)

DEVI unsigned short f2bf(float f) {
  unsigned u = __float_as_uint(f);
  u += 0x7fffu + ((u >> 16) & 1u);
  return (unsigned short)(u >> 16);
}
DEVI float bf2f(unsigned short h) { return __uint_as_float(((unsigned)h) << 16); }

DEVI void gl_lds16(const unsigned short* g, unsigned short* l) {
  __builtin_amdgcn_global_load_lds((const __attribute__((address_space(1))) unsigned int*)g,
                                   (__attribute__((address_space(3))) unsigned int*)l, 16, 0, 0);
}

// ------- fused weight transpose + f32->bf16 for all 4 weights, one launch -------
__global__ __launch_bounds__(256) void wt_cvt_all_kernel(const float* __restrict__ qkv_w,
                                                         const float* __restrict__ merge_w,
                                                         const float* __restrict__ ln1_w,
                                                         const float* __restrict__ ln2_w,
                                                         unsigned short* __restrict__ qkv_wT,
                                                         unsigned short* __restrict__ merge_wT,
                                                         unsigned short* __restrict__ ln1_wT,
                                                         unsigned short* __restrict__ ln2_wT) {
  __shared__ float tl[32][33];
  int bid = blockIdx.x;
  const float* W;
  unsigned short* Wt;
  int K, N, bx, by;
  if (bid < 3072) {
    W = qkv_w; Wt = qkv_wT; K = 1024; N = 3072; bx = bid % 96; by = bid / 96;
  } else if (bid < 4096) {
    int b2 = bid - 3072; W = merge_w; Wt = merge_wT; K = 1024; N = 1024; bx = b2 % 32; by = b2 / 32;
  } else if (bid < 8192) {
    int b3 = bid - 4096; W = ln1_w; Wt = ln1_wT; K = 1024; N = 4096; bx = b3 % 128; by = b3 / 128;
  } else {
    int b4 = bid - 8192; W = ln2_w; Wt = ln2_wT; K = 4096; N = 1024; bx = b4 % 32; by = b4 / 32;
  }
  int n0 = bx * 32, k0 = by * 32;
  int tx = threadIdx.x & 31, ty = threadIdx.x >> 5;
#pragma unroll
  for (int j = 0; j < 4; j++)
    tl[ty + 8 * j][tx] = W[(long)(k0 + ty + 8 * j) * N + n0 + tx];
  __syncthreads();
#pragma unroll
  for (int j = 0; j < 4; j++)
    Wt[(long)(n0 + ty + 8 * j) * K + k0 + tx] = f2bf(tl[tx][ty + 8 * j]);
}

// ---------------- layernorm ----------------
__global__ __launch_bounds__(256) void ln_kernel(const float* __restrict__ x,
                                                 const float* __restrict__ g,
                                                 const float* __restrict__ bia,
                                                 unsigned short* __restrict__ out) {
  int row = blockIdx.x;
  int t = threadIdx.x;
  const float4* xr = (const float4*)(x + (long)row * Dd);
  float4 v = xr[t];
  float s1 = v.x + v.y + v.z + v.w;
  float s2 = v.x * v.x + v.y * v.y + v.z * v.z + v.w * v.w;
#pragma unroll
  for (int o = 1; o < 64; o <<= 1) {
    s1 += __shfl_xor(s1, o);
    s2 += __shfl_xor(s2, o);
  }
  __shared__ float r1[4], r2[4];
  int wid = t >> 6;
  if ((t & 63) == 0) { r1[wid] = s1; r2[wid] = s2; }
  __syncthreads();
  s1 = r1[0] + r1[1] + r1[2] + r1[3];
  s2 = r2[0] + r2[1] + r2[2] + r2[3];
  float mean = s1 * (1.0f / Dd);
  float var = s2 * (1.0f / Dd) - mean * mean;
  float rstd = rsqrtf(var + 1e-3f);
  float4 gg = ((const float4*)g)[t];
  float4 bb = ((const float4*)bia)[t];
  ushort4 o;
  o.x = f2bf((v.x - mean) * rstd * gg.x + bb.x);
  o.y = f2bf((v.y - mean) * rstd * gg.y + bb.y);
  o.z = f2bf((v.z - mean) * rstd * gg.z + bb.z);
  o.w = f2bf((v.w - mean) * rstd * gg.w + bb.w);
  *((ushort4*)(out + (long)row * Dd + t * 4)) = o;
}

// ---- prep: present (from c) + kp16 (past K) + vT past cols + vT new cols ----
__global__ __launch_bounds__(256) void prep_kernel(const unsigned short* __restrict__ c,
                                                   const float* __restrict__ past,
                                                   float* __restrict__ present,
                                                   unsigned short* __restrict__ kp16,
                                                   unsigned short* __restrict__ vT) {
  __shared__ unsigned short Tl[64 * 72];
  long bid = blockIdx.x;
  if (bid < 16384) {
    long i = bid * 256 + threadIdx.x;
    int dh = (int)(i & 63);
    int s = (int)((i >> 6) & 2047);
    int h = (int)((i >> 17) & 15);
    int b = (int)(i >> 21);
    long crow = ((long)b * Ss + s) * (3 * Dd) + h * DHh + dh;
    unsigned short kv = c[crow + Dd];
    unsigned short vv = c[crow + 2 * Dd];
    present[((((long)b * 2 + 0) * Hh + h) * Ss + s) * DHh + dh] = bf2f(kv);
    present[((((long)b * 2 + 1) * Hh + h) * Ss + s) * DHh + dh] = bf2f(vv);
  } else if (bid < 17408) {
    long j = (bid - 16384) * 256 + threadIdx.x;
    int dh = (int)(j & 63);
    int p = (int)((j >> 6) & 127);
    int z = (int)(j >> 13);
    int b = z >> 4, h = z & 15;
    float pk = past[((((long)b * 2 + 0) * Hh + h) * Pp + p) * DHh + dh];
    kp16[((long)z * Pp + p) * DHh + dh] = f2bf(pk);
  } else if (bid < 18432) {
    long j = (bid - 17408) * 256 + threadIdx.x;
    int p = (int)(j & 127);
    int dh = (int)((j >> 7) & 63);
    int z = (int)(j >> 13);
    int b = z >> 4, h = z & 15;
    float pv = past[((((long)b * 2 + 1) * Hh + h) * Pp + p) * DHh + dh];
    vT[((long)z * DHh + dh) * NS + p] = f2bf(pv);
  } else {
    int bid2 = (int)(bid - 18432);
    int z = bid2 >> 5;
    int b = z >> 4, h = z & 15;
    int s0 = Pp + (bid2 & 31) * 64;
    int t = threadIdx.x;
#pragma unroll
    for (int it = 0; it < 2; it++) {
      int idx = t + it * 256, row = idx >> 3, c8 = (idx & 7) * 8;
      *(short8*)&Tl[row * 72 + c8] =
          *(const short8*)(c + ((long)b * Ss + s0 - Pp + row) * (3 * Dd) + 2 * Dd + h * DHh + c8);
    }
    __syncthreads();
#pragma unroll
    for (int it = 0; it < 2; it++) {
      int idx = t + it * 256, row = idx >> 3, c8 = (idx & 7) * 8;
      short8 g;
#pragma unroll
      for (int e = 0; e < 8; e++) g[e] = (short)Tl[(c8 + e) * 72 + row];
      *(short8*)(vT + ((long)z * DHh + row) * NS + s0 + c8) = g;
    }
  }
}

// ---- fused attention (two-pass, fixed-max softmax); Q/K sourced from c + kp16 ----
__global__ __launch_bounds__(256) void attn_kernel(const unsigned short* __restrict__ c,
                                                   const unsigned short* __restrict__ kp16,
                                                   const unsigned short* __restrict__ vTg,
                                                   float* __restrict__ wg,
                                                   unsigned short* __restrict__ am) {
  __shared__ unsigned short KV[128 * 72];
  __shared__ unsigned short Pl[128 * 136];
  int wgs = (blockIdx.x & 7) * 64 + (blockIdx.x >> 3);
  int z = wgs >> 4;
  int bx = 15 - (wgs & 15);
  int q0 = bx * 128;
  int bq = z >> 4, hh = z & 15;
  int t = threadIdx.x, lane = t & 63, wid = t >> 6;
  int lr = lane & 15, kgp = lane >> 4;
  const unsigned short* cb = c + (long)bq * Ss * (3 * Dd) + hh * DHh;
  const unsigned short* kp = kp16 + (long)z * Pp * DHh;
  const unsigned short* vz = vTg + (long)z * DHh * NS;
  float* wz = wg + (long)z * Ss * NS;

  short8 qa[2][2];
#pragma unroll
  for (int i = 0; i < 2; i++)
#pragma unroll
    for (int kk = 0; kk < 2; kk++)
      qa[i][kk] = *(const short8*)(cb + (long)(q0 + wid * 32 + i * 16 + lr) * (3 * Dd) +
                                   kk * 32 + kgp * 8);

  const int nt = bx + 2;
  float l_run[2][4] = {};

#define STAGE_K(kt_)                                                                   \
  do {                                                                                 \
    if ((kt_) == 0) {                                                                  \
      _Pragma("unroll") for (int it = 0; it < 4; it++) {                               \
        int idx = t + it * 256, row = idx >> 3, c8 = (idx & 7) * 8;                    \
        *(short8*)&KV[row * 72 + c8] = *(const short8*)(kp + (long)row * DHh + c8);    \
      }                                                                                \
    } else {                                                                           \
      _Pragma("unroll") for (int it = 0; it < 4; it++) {                               \
        int idx = t + it * 256, row = idx >> 3, c8 = (idx & 7) * 8;                    \
        *(short8*)&KV[row * 72 + c8] = *(const short8*)(                               \
            cb + (long)(((kt_)-1) * 128 + row) * (3 * Dd) + Dd + c8);                  \
      }                                                                                \
    }                                                                                  \
  } while (0)

  // ---- pass 1: denominators (fixed max M0=8) ----
  for (int kt = 0; kt < nt; kt++) {
    STAGE_K(kt);
    SYNC_LDS();
    floatx4 acc[2][8] = {};
    __builtin_amdgcn_s_setprio(1);
#pragma unroll
    for (int j = 0; j < 8; j++) {
      short8 b0 = *(const short8*)&KV[(j * 16 + lr) * 72 + kgp * 8];
      short8 b1 = *(const short8*)&KV[(j * 16 + lr) * 72 + 32 + kgp * 8];
#pragma unroll
      for (int i = 0; i < 2; i++) {
        acc[i][j] = __builtin_amdgcn_mfma_f32_16x16x32_bf16(qa[i][0], b0, acc[i][j], 0, 0, 0);
        acc[i][j] = __builtin_amdgcn_mfma_f32_16x16x32_bf16(qa[i][1], b1, acc[i][j], 0, 0, 0);
      }
    }
    __builtin_amdgcn_s_setprio(0);
#pragma unroll
    for (int i = 0; i < 2; i++) {
#pragma unroll
      for (int r = 0; r < 4; r++) {
        int row = q0 + wid * 32 + i * 16 + kgp * 4 + r;
        float su = 0.f;
#pragma unroll
        for (int j = 0; j < 8; j++) {
          int col = kt * 128 + j * 16 + lr;
          su += (col > row + Pp) ? 0.f : __expf(acc[i][j][r] * 0.125f - 8.0f);
        }
        su += __shfl_xor(su, 1);
        su += __shfl_xor(su, 2);
        su += __shfl_xor(su, 4);
        su += __shfl_xor(su, 8);
        l_run[i][r] += su;
      }
    }
    SYNC_LDS();
  }

  float cc[2][4];
#pragma unroll
  for (int i = 0; i < 2; i++)
#pragma unroll
    for (int r = 0; r < 4; r++) cc[i][r] = 8.0f + __logf(l_run[i][r]);

  // ---- pass 2: w + PV ----
  floatx4 oacc[2][4] = {};
  for (int kt = 0; kt < nt; kt++) {
    STAGE_K(kt);
    SYNC_LDS();
    floatx4 acc[2][8] = {};
    __builtin_amdgcn_s_setprio(1);
#pragma unroll
    for (int j = 0; j < 8; j++) {
      short8 b0 = *(const short8*)&KV[(j * 16 + lr) * 72 + kgp * 8];
      short8 b1 = *(const short8*)&KV[(j * 16 + lr) * 72 + 32 + kgp * 8];
#pragma unroll
      for (int i = 0; i < 2; i++) {
        acc[i][j] = __builtin_amdgcn_mfma_f32_16x16x32_bf16(qa[i][0], b0, acc[i][j], 0, 0, 0);
        acc[i][j] = __builtin_amdgcn_mfma_f32_16x16x32_bf16(qa[i][1], b1, acc[i][j], 0, 0, 0);
      }
    }
    __builtin_amdgcn_s_setprio(0);
#pragma unroll
    for (int i = 0; i < 2; i++) {
#pragma unroll
      for (int r = 0; r < 4; r++) {
        int row = q0 + wid * 32 + i * 16 + kgp * 4 + r;
#pragma unroll
        for (int j = 0; j < 8; j++) {
          int col = kt * 128 + j * 16 + lr;
          float p = (col > row + Pp) ? 0.f : __expf(acc[i][j][r] * 0.125f - cc[i][r]);
          Pl[(wid * 32 + i * 16 + kgp * 4 + r) * 136 + j * 16 + lr] = f2bf(p);
        }
      }
    }
    SYNC_LDS();
#pragma unroll
    for (int it = 0; it < 4; it++) {
      int idx = t + it * 256, row = idx >> 4, c8 = (idx & 15) * 8;
      *(short8*)&KV[row * 136 + c8] = *(const short8*)(vz + (long)row * NS + kt * 128 + c8);
    }
    {
      int prow = t >> 5, pcol = (t & 31) * 4;
#pragma unroll
      for (int it = 0; it < 16; it++) {
        int row = it * 8 + prow;
        float4 f;
        f.x = bf2f(Pl[row * 136 + pcol]);
        f.y = bf2f(Pl[row * 136 + pcol + 1]);
        f.z = bf2f(Pl[row * 136 + pcol + 2]);
        f.w = bf2f(Pl[row * 136 + pcol + 3]);
        *(float4*)&wz[(long)(q0 + row) * NS + kt * 128 + pcol] = f;
      }
    }
    SYNC_LDS();
    __builtin_amdgcn_s_setprio(1);
#pragma unroll
    for (int kk = 0; kk < 4; kk++) {
      short8 pa[2];
#pragma unroll
      for (int i = 0; i < 2; i++)
        pa[i] = *(const short8*)&Pl[(wid * 32 + i * 16 + lr) * 136 + kk * 32 + kgp * 8];
#pragma unroll
      for (int jd = 0; jd < 4; jd++) {
        short8 bv = *(const short8*)&KV[(jd * 16 + lr) * 136 + kk * 32 + kgp * 8];
#pragma unroll
        for (int i = 0; i < 2; i++)
          oacc[i][jd] = __builtin_amdgcn_mfma_f32_16x16x32_bf16(pa[i], bv, oacc[i][jd], 0, 0, 0);
      }
    }
    __builtin_amdgcn_s_setprio(0);
    SYNC_LDS();
  }
#undef STAGE_K

  int zc0 = nt * 128;
  if (zc0 < NS) {
    for (int rr = 0; rr < 32; rr++) {
      int row = q0 + wid * 32 + rr;
      for (int cix = zc0 + (lane << 2); cix < NS; cix += 256) {
        float4 z4 = {0.f, 0.f, 0.f, 0.f};
        *(float4*)&wz[(long)row * NS + cix] = z4;
      }
    }
  }

#pragma unroll
  for (int i = 0; i < 2; i++)
#pragma unroll
    for (int jd = 0; jd < 4; jd++)
#pragma unroll
      for (int r = 0; r < 4; r++) {
        long row = (long)bq * Ss + q0 + wid * 32 + i * 16 + kgp * 4 + r;
        int col = hh * 64 + jd * 16 + lr;
        am[row * Dd + col] = f2bf(oacc[i][jd][r]);
      }
}

enum { EPI_BF16_BIAS = 0, EPI_RES = 3, EPI_GELU = 4 };

DEVI void epilogue_one(int EPIv, void* outv, const float* bias, const float* res,
                       int N, int mm, int nn, float v) {
  if (EPIv == EPI_BF16_BIAS) {
    ((unsigned short*)outv)[(long)mm * N + nn] = f2bf(v + bias[nn]);
  } else if (EPIv == EPI_RES) {
    ((float*)outv)[(long)mm * N + nn] = v + bias[nn] + res[(long)mm * N + nn];
  } else {
    float xv = v + bias[nn];
    float u = xv + 0.044715f * xv * xv * xv;
    float tv = 1.0f - 2.0f / (__expf(1.5957691216057308f * u) + 1.0f);
    ((unsigned short*)outv)[(long)mm * N + nn] = f2bf(0.5f * xv * (1.0f + tv));
  }
}

// --- 128-class bf16 MFMA GEMM (2-phase dbuf) for merge / MLP2 ---
template <int EPI, int BM, int BN, int NB>
__global__ __launch_bounds__(256) void gemm_k(const unsigned short* __restrict__ A16,
                                              const unsigned short* __restrict__ Bt,
                                              const float* __restrict__ bias,
                                              const float* __restrict__ res,
                                              void* __restrict__ outv,
                                              int M, int N, int K, int nwg) {
  constexpr int WTM = BM / 2, WTN = BN / 2;
  constexpr int FM = WTM / 16, FN = WTN / 16;
  constexpr int IA = BM / 64, IB = BN / 64;
  __shared__ unsigned short Alds[2][BM * 32];
  __shared__ unsigned short Blds[2][BN * 32];
  int cpx = nwg >> 3;
  int wgid = (blockIdx.x & 7) * cpx + (blockIdx.x >> 3);
  int mb = wgid / NB, nb = wgid % NB;
  int m0 = mb * BM, n0 = nb * BN;
  int t = threadIdx.x;
  int lane = t & 63, wid = t >> 6;
  int wm = wid >> 1, wn = wid & 1;
  floatx4 acc[FM][FN] = {};
  int lr = lane & 15, kg = lane >> 4;

  int srow = lane >> 2, skc = (lane & 3) * 8;
  const unsigned short* Ab = A16 + (long)(m0 + wid * (BM / 4) + srow) * K + skc;
  const unsigned short* Bp = Bt + (long)(n0 + wid * (BN / 4) + srow) * K + skc;
  long rstride = (long)16 * K;

#define STAGE(bb, k0)                                                         \
  do {                                                                        \
    _Pragma("unroll") for (int ii = 0; ii < IA; ii++)                         \
        gl_lds16(Ab + ii * rstride + (k0),                                    \
                 &Alds[bb][(wid * (BM / 4) + ii * 16) * 32]);                 \
    _Pragma("unroll") for (int ii = 0; ii < IB; ii++)                         \
        gl_lds16(Bp + ii * rstride + (k0),                                    \
                 &Blds[bb][(wid * (BN / 4) + ii * 16) * 32]);                 \
  } while (0)

  STAGE(0, 0);
  SYNC_VM();
  int cur = 0;
  int nt = K >> 5;
  for (int tt = 0; tt < nt; tt++) {
    if (tt + 1 < nt) STAGE(cur ^ 1, (tt + 1) * 32);
    short8 a[FM], b[FN];
#pragma unroll
    for (int i = 0; i < FM; i++)
      a[i] = *(const short8*)&Alds[cur][(wm * WTM + i * 16 + lr) * 32 + kg * 8];
#pragma unroll
    for (int j = 0; j < FN; j++)
      b[j] = *(const short8*)&Blds[cur][(wn * WTN + j * 16 + lr) * 32 + kg * 8];
    __builtin_amdgcn_s_setprio(1);
#pragma unroll
    for (int i = 0; i < FM; i++)
#pragma unroll
      for (int j = 0; j < FN; j++)
        acc[i][j] = __builtin_amdgcn_mfma_f32_16x16x32_bf16(a[i], b[j], acc[i][j], 0, 0, 0);
    __builtin_amdgcn_s_setprio(0);
    SYNC_VM();
    cur ^= 1;
  }
#undef STAGE

#pragma unroll
  for (int i = 0; i < FM; i++)
#pragma unroll
    for (int j = 0; j < FN; j++)
#pragma unroll
      for (int r = 0; r < 4; r++)
        epilogue_one(EPI, outv, bias, res, N,
                     m0 + wm * WTM + i * 16 + kg * 4 + r,
                     n0 + wn * WTN + j * 16 + lr, acc[i][j][r]);
}

// --- 256x256 counted-vmcnt GEMM (T3+T4+T2): BK=64, 512 thr, 2-buffer ring ---
// Sync ledger per K-tile t (buffers: cur=t&1):
//   vmcnt(8): own tile-t loads done (tile t+1's 8 stay in flight; never drain in loop)
//   barrier : all waves' tile-t loads done -> safe to read buf[cur]
//   24 ds_read (XOR-swizzled) + 64 MFMA (setprio-wrapped)
//   barrier : all waves done reading buf[cur]
//   stage tile t+2 -> buf[cur] (8 gload_lds; lands during iters t+1..t+2)
// Swizzle (both-sides, rule 21): LDS[row*64 + g*8] = Global[row, (g^(row&7))*8]
//   write: linear dest; lane l of an 8-row issue reads global granule (l&7)^(l>>3)
//   read : granule' = (kks*4+kg) ^ (lr&7)  -> 2-way bank aliasing (free)
template <int EPI, int NB>
__global__ __launch_bounds__(512, 2) void gemm256_k(const unsigned short* __restrict__ A16,
                                                    const unsigned short* __restrict__ Bt,
                                                    const float* __restrict__ bias,
                                                    const float* __restrict__ res,
                                                    void* __restrict__ outv,
                                                    int M, int N, int K, int nwg) {
  __shared__ unsigned short Al[2][256 * 64];
  __shared__ unsigned short Bl[2][256 * 64];
  int cpx = nwg >> 3;
  int wgid = (blockIdx.x & 7) * cpx + (blockIdx.x >> 3);
  int mb = wgid / NB, nb = wgid % NB;
  int m0 = mb * 256, n0 = nb * 256;
  int tid = threadIdx.x;
  int lane = tid & 63, w = tid >> 6;
  int wm = w >> 2, wn = w & 3; // 2M x 4N waves; per-wave output 128x64
  int lr = lane & 15, kg = lane >> 4;
  int l7 = lane & 7;
  floatx4 acc[8][4] = {};

  // staging: wave w stages rows [w*32, w*32+32) of A and B as 4 issues x 8 rows (1KB each)
  int rl = lane >> 3;       // row within 8-row issue chunk
  int sg = (lane & 7) ^ rl; // pre-swizzled source granule
  const unsigned short* Asrc = A16 + (long)(m0 + w * 32 + rl) * K + sg * 8;
  const unsigned short* Bsrc = Bt + (long)(n0 + w * 32 + rl) * K + sg * 8;
  long r8 = (long)8 * K;
  int ldsbase = w * 32 * 64; // elements; linear dest (lane*16B added by HW)

#define STAGE_TILE(bb, kt)                                              \
  do {                                                                  \
    long ko = (long)(kt) * 64;                                          \
    _Pragma("unroll") for (int ii = 0; ii < 4; ii++) {                  \
      gl_lds16(Asrc + ii * r8 + ko, &Al[bb][ldsbase + ii * 512]);       \
      gl_lds16(Bsrc + ii * r8 + ko, &Bl[bb][ldsbase + ii * 512]);       \
    }                                                                   \
  } while (0)

  int ntk = K >> 6;
  STAGE_TILE(0, 0);
  if (ntk > 1) STAGE_TILE(1, 1);

  for (int t = 0; t < ntk; t++) {
    int cur = t & 1;
    if (t + 1 < ntk) {
      asm volatile("s_waitcnt vmcnt(8)" ::: "memory"); // counted: tile t done, t+1 in flight
    } else {
      asm volatile("s_waitcnt vmcnt(0)" ::: "memory"); // last tile: nothing newer
    }
    __builtin_amdgcn_s_barrier();
    const unsigned short* Ac = &Al[cur][0];
    const unsigned short* Bc = &Bl[cur][0];
    short8 bf[4][2];
#pragma unroll
    for (int fn = 0; fn < 4; fn++)
#pragma unroll
      for (int kks = 0; kks < 2; kks++)
        bf[fn][kks] = *(const short8*)&Bc[(wn * 64 + fn * 16 + lr) * 64 +
                                          (((kks * 4 + kg) ^ l7) * 8)];
    __builtin_amdgcn_s_setprio(1);
#pragma unroll
    for (int p = 0; p < 4; p++) {
      short8 af[2][2];
#pragma unroll
      for (int q = 0; q < 2; q++)
#pragma unroll
        for (int kks = 0; kks < 2; kks++)
          af[q][kks] = *(const short8*)&Ac[(wm * 128 + (p * 2 + q) * 16 + lr) * 64 +
                                            (((kks * 4 + kg) ^ l7) * 8)];
#pragma unroll
      for (int q = 0; q < 2; q++)
#pragma unroll
        for (int fn = 0; fn < 4; fn++)
#pragma unroll
          for (int kks = 0; kks < 2; kks++)
            acc[p * 2 + q][fn] = __builtin_amdgcn_mfma_f32_16x16x32_bf16(
                af[q][kks], bf[fn][kks], acc[p * 2 + q][fn], 0, 0, 0);
    }
    __builtin_amdgcn_s_setprio(0);
    __builtin_amdgcn_s_barrier(); // all waves done reading buf[cur]
    if (t + 2 < ntk) STAGE_TILE(cur, t + 2);
  }
#undef STAGE_TILE

#pragma unroll
  for (int fm = 0; fm < 8; fm++)
#pragma unroll
    for (int fn = 0; fn < 4; fn++)
#pragma unroll
      for (int r = 0; r < 4; r++)
        epilogue_one(EPI, outv, bias, res, N,
                     m0 + wm * 128 + fm * 16 + kg * 4 + r,
                     n0 + wn * 64 + fn * 16 + lr, acc[fm][fn][r]);
}

extern "C" void kernel_launch(void* const* d_in, const int* in_sizes, int n_in,
                              void* d_out, int out_size, void* d_ws, size_t ws_size,
                              hipStream_t stream) {
  (void)in_sizes; (void)n_in; (void)out_size; (void)ws_size;
  const float* x = (const float*)d_in[0];
  const float* past = (const float*)d_in[1];
  const float* qkv_w = (const float*)d_in[2];
  const float* qkv_b = (const float*)d_in[3];
  const float* merge_w = (const float*)d_in[4];
  const float* merge_b = (const float*)d_in[5];
  const float* ln1_w = (const float*)d_in[6];
  const float* ln1_b = (const float*)d_in[7];
  const float* ln2_w = (const float*)d_in[8];
  const float* ln2_b = (const float*)d_in[9];
  const float* g1 = (const float*)d_in[10];
  const float* b1 = (const float*)d_in[11];
  const float* g2 = (const float*)d_in[12];
  const float* b2 = (const float*)d_in[13];

  char* ws = (char*)d_ws;
  unsigned short* qkv_wT = (unsigned short*)(ws + 0);
  unsigned short* merge_wT = (unsigned short*)(ws + 6291456);
  unsigned short* ln1_wT = (unsigned short*)(ws + 8388608);
  unsigned short* ln2_wT = (unsigned short*)(ws + 16777216);
  unsigned short* h = (unsigned short*)(ws + 25165824);
  unsigned short* am = (unsigned short*)(ws + 33554432);
  unsigned short* kp16 = (unsigned short*)(ws + 41943040);
  unsigned short* vT = (unsigned short*)(ws + 50855936);
  unsigned short* c = (unsigned short*)(ws + 59768832);
  unsigned short* m1 = (unsigned short*)(ws + 25165824);
  float* xa = (float*)(ws + 68157440);
  unsigned short* h2 = (unsigned short*)(ws + 84934656);

  float* xm_out = (float*)d_out;
  float* present = ((float*)d_out) + (long)Bb * Ss * Dd;
  float* w_out = present + (long)Bb * 2 * Hh * Ss * DHh;

  wt_cvt_all_kernel<<<12288, 256, 0, stream>>>(qkv_w, merge_w, ln1_w, ln2_w,
                                               qkv_wT, merge_wT, ln1_wT, ln2_wT);

  ln_kernel<<<Bb * Ss, 256, 0, stream>>>(x, g1, b1, h);

  // c = LN(x) @ qkv_w + qkv_b  (256^2 counted-vmcnt, 192 blocks)
  gemm256_k<EPI_BF16_BIAS, 12><<<192, 512, 0, stream>>>(
      h, qkv_wT, qkv_b, nullptr, c, 4096, 3072, 1024, 192);

  prep_kernel<<<19456, 256, 0, stream>>>(c, past, present, kp16, vT);

  attn_kernel<<<512, 256, 0, stream>>>(c, kp16, vT, w_out, am);

  gemm_k<EPI_RES, 64, 128, 8><<<64 * 8, 256, 0, stream>>>(
      am, merge_wT, merge_b, x, xa, 4096, 1024, 1024, 64 * 8);

  ln_kernel<<<Bb * Ss, 256, 0, stream>>>(xa, g2, b2, h2);

  // m1 = gelu(h2 @ ln1_w + ln1_b)  (256^2 counted-vmcnt, 256 blocks = 1/CU)
  gemm256_k<EPI_GELU, 16><<<256, 512, 0, stream>>>(
      h2, ln1_wT, ln1_b, nullptr, m1, 4096, 4096, 1024, 256);

  gemm_k<EPI_RES, 64, 128, 8><<<64 * 8, 256, 0, stream>>>(
      m1, ln2_wT, ln2_b, x, xm_out, 4096, 1024, 4096, 64 * 8);
}